// Round 14
// baseline (300.215 us; speedup 1.0000x reference)
//
#include <hip/hip_runtime.h>

// LSTM B=4096, T=512, I=2, H=50, O=3 — MFMA, round 14.
// vs r13: ZERO vector-memory ops inside the t-loop.
//  * x staged ONCE into LDS as bf16 pairs (32 KB, [row][t] 4B): the per-t
//    global load + its zero-shadow vmcnt(0) pre-barrier drain (r13's
//    straggler: x-writer wave drained a cold-ish load EVERY t) are gone.
//  * no x-writer wave at all: every lane does one extra ds_read_b32 of its
//    col's x(t); grp==3 lanes substitute it into reg0 of their kt=1 B-frag
//    (granule 7 = k56..63, never written by h, stays zero elsewhere).
//    A-side: k=56/57 = W_ih cols (hi/lo, scale-folded), k=50 = bias
//    (B-value 1.0 written once per buffer). Loop drain = lgkmcnt only.
//  * 7 waves (448 thr) x 2 tiles = 14 tiles (13 real), 256 blocks.
// K map: k<50 h(bf16), 50 bias, 56/57 x0/x1 (bf16-hi), else 0.
//   A (M) = weight rows (scaled, hi/lo VGPR frags), m=col: u=tau*4+(col>>2),
//           gate=col&3;  B (N) = h/x/bias, n-col = batch row.
//   C: col=lane&15=batch, grp=lane>>4=unit-in-tile, reg=GATE
// ONE barrier per t. Double-buffered h planes. Epilogue: exp2-direct,
// merged-rcp (scales pre-folded into A).

typedef short bf16x8 __attribute__((ext_vector_type(8)));
typedef float f32x4  __attribute__((ext_vector_type(4)));

#define T_STEPS 512
#define HID     50
#define ROWS    16
#define RS      144                        // bytes per m-row (9 granules)
#define HBUF_SZ (ROWS * RS)                // 2304 B
#define XS_OFF  (2 * HBUF_SZ)              // 4608 B
#define XS_SZ   (ROWS * T_STEPS * 4)       // 32768 B (bf16 pair per [row][t])
#define HF_OFF  (XS_OFF + XS_SZ)           // 37376 B
#define ARENA_SZ (HF_OFF + ROWS * 64 * 4)  // 41472 B
#define NTHREADS 448

#define L2E  1.442695040888963f
#define L2E2 2.885390081777927f

// init-time RTN bf16 hi/lo split (lo short = hi(f), hi short = residual)
__device__ __forceinline__ unsigned pack_hilo(float f) {
    unsigned u  = __float_as_uint(f);
    unsigned hi = (u + 0x7fffu + ((u >> 16) & 1u)) >> 16;
    float    fh = __uint_as_float(hi << 16);
    float    rl = f - fh;
    unsigned ul = __float_as_uint(rl);
    unsigned lo = (ul + 0x7fffu + ((ul >> 16) & 1u)) >> 16;
    return (hi & 0xFFFFu) | (lo << 16);
}
// 1-instr packed bf16 RNE: low short = bf16(a), high short = bf16(b)
__device__ __forceinline__ unsigned cvt_pk_bf16(float a, float b) {
    unsigned r;
    asm("v_cvt_pk_bf16_f32 %0, %1, %2" : "=v"(r) : "v"(a), "v"(b));
    return r;
}

__global__ __launch_bounds__(NTHREADS) void lstm_mfma10_kernel(
    const float* __restrict__ x,     // [B,T,2]
    const float* __restrict__ W_ih,  // [200,2]
    const float* __restrict__ W_hh,  // [200,50]
    const float* __restrict__ b_ih,  // [200]
    const float* __restrict__ b_hh,  // [200]
    const float* __restrict__ W_fc,  // [3,50]
    const float* __restrict__ b_fc,  // [3]
    float* __restrict__ out)         // [B,3]
{
    __shared__ __align__(16) char arena[ARENA_SZ];

    const int tid  = threadIdx.x;
    const int lane = tid & 63;
    const int wvf  = tid >> 6;         // wave 0..6
    const int col  = lane & 15;        // C col = batch row; A row index m
    const int grp  = lane >> 4;        // k-group; C row-group = unit-in-tile
    const int b0   = blockIdx.x * ROWS;

    // ---- zero h buffers + hf (xstage fully overwritten below) ----
    for (int i = tid; i < XS_OFF / 4; i += NTHREADS) ((int*)arena)[i] = 0;
    for (int i = tid; i < (ARENA_SZ - HF_OFF) / 4; i += NTHREADS)
        ((int*)(arena + HF_OFF))[i] = 0;

    // ---- stage x -> LDS bf16 pairs: xstage[row*512 + t] = pk(x0,x1) ----
    {
        unsigned* xs = (unsigned*)(arena + XS_OFF);
        for (int idx = tid; idx < ROWS * T_STEPS; idx += NTHREADS) {
            int row = idx >> 9;          // idx = row*512 + t
            int t   = idx & (T_STEPS - 1);
            float2 v = *(const float2*)(x + (size_t)(b0 + row) * (T_STEPS * 2) + t * 2);
            xs[idx] = cvt_pk_bf16(v.x, v.y);
        }
    }

    // ---- A-frags (scaled weights, hi/lo) for tiles tau = 2*wvf + tt ----
    bf16x8 awhi[2][2], awlo[2][2];   // [tt][kt]
    bool act[2];
#pragma unroll
    for (int tt = 0; tt < 2; ++tt) {
        const int tau = wvf * 2 + tt;
        act[tt] = (tau * 4) < HID;
        const int u = tau * 4 + (col >> 2);
        const int g = col & 3;
        const float s = (g == 2) ? L2E2 : -L2E;   // fold gate scale into A
#pragma unroll
        for (int kt = 0; kt < 2; ++kt) {
            bf16x8 H, L;
#pragma unroll
            for (int e = 0; e < 8; ++e) {
                int k = kt * 32 + grp * 8 + e;
                float v = 0.f;
                if (act[tt] && u < HID) {
                    int j = g * HID + u;
                    if      (k < HID)  v = W_hh[j * HID + k];
                    else if (k == 50)  v = b_ih[j] + b_hh[j];   // bias slot
                    else if (k == 56)  v = W_ih[2 * j + 0];     // x0 slot
                    else if (k == 57)  v = W_ih[2 * j + 1];     // x1 slot
                }
                unsigned p = pack_hilo(v * s);
                H[e] = (short)(p & 0xFFFFu);
                L[e] = (short)(p >> 16);
            }
            awhi[tt][kt] = H;
            awlo[tt][kt] = L;
        }
    }

    __syncthreads();   // zeroing + xstage complete

    // bias multiplier: B-value 1.0 at k=50 (granule 6, byte 100), both buffers
    if (tid < 2 * ROWS) {
        int buf = tid >> 4, m = tid & 15;
        *(short*)(arena + buf * HBUF_SZ + m * RS + 100) = (short)0x3F80;
    }

    float c2[2]   = {0.f, 0.f};
    float hreg[2] = {0.f, 0.f};
    const bool isg3 = (grp == 3);
    const char* xsp = arena + XS_OFF + col * (T_STEPS * 4);   // my col's x row

    __syncthreads();

    int pb = 0;
    for (int t = 0; t < T_STEPS; ++t) {
        char* db = arena + (pb ^ 1) * HBUF_SZ;

        // ---- B-frags: 2x ds_read_b128 (+1 ds_read_b32 for x) ----
        const char* hb = arena + pb * HBUF_SZ + col * RS + grp * 16;
        bf16x8 bh0 = *(const bf16x8*)(hb);
        union { unsigned d[4]; bf16x8 v; } B1;
        B1.v = *(const bf16x8*)(hb + 64);
        unsigned xv = *(const unsigned*)(xsp + 4 * t);
        if (isg3) B1.d[0] = xv;          // k=56/57 slots <- x(t) (cndmask)
        bf16x8 bh1 = B1.v;

        // ---- per tile: 4 MFMA in two independent 2-chains ----
        f32x4 acc[2];
#pragma unroll
        for (int tt = 0; tt < 2; ++tt) {
            if (!act[tt]) continue;
            f32x4 a0 = {0.f, 0.f, 0.f, 0.f};
            f32x4 a1 = {0.f, 0.f, 0.f, 0.f};
            a0 = __builtin_amdgcn_mfma_f32_16x16x32_bf16(awhi[tt][0], bh0, a0, 0, 0, 0);
            a1 = __builtin_amdgcn_mfma_f32_16x16x32_bf16(awhi[tt][1], bh1, a1, 0, 0, 0);
            a0 = __builtin_amdgcn_mfma_f32_16x16x32_bf16(awlo[tt][0], bh0, a0, 0, 0, 0);
            a1 = __builtin_amdgcn_mfma_f32_16x16x32_bf16(awlo[tt][1], bh1, a1, 0, 0, 0);
            acc[tt] = a0 + a1;
        }

        // ---- epilogue: scales pre-folded -> exp2 direct, merged rcp ----
#pragma unroll
        for (int tt = 0; tt < 2; ++tt) {
            if (!act[tt]) continue;
            const int u = (wvf * 2 + tt) * 4 + grp;
            float ei = __builtin_amdgcn_exp2f(acc[tt][0]);
            float ef = __builtin_amdgcn_exp2f(acc[tt][1]);
            float eg = __builtin_amdgcn_exp2f(acc[tt][2]);
            float eo = __builtin_amdgcn_exp2f(acc[tt][3]);
            float sf    = __builtin_amdgcn_rcpf(1.0f + ef);
            float ig_tg = (eg - 1.0f) * __builtin_amdgcn_rcpf((1.0f + ei) * (eg + 1.0f));
            float c = sf * c2[tt] + ig_tg;
            c = fminf(fmaxf(c, -32.0f), 32.0f);
            c2[tt] = c;
            float ec = __builtin_amdgcn_exp2f(L2E2 * c);
            float h  = (ec - 1.0f) * __builtin_amdgcn_rcpf((1.0f + eo) * (ec + 1.0f));
            hreg[tt] = h;
            if (u < HID) {
                unsigned hp = cvt_pk_bf16(h, h);
                *(short*)(db + col * RS + u * 2) = (short)(hp & 0xFFFFu);
            }
        }

        pb ^= 1;
        __syncthreads();
    }

    // ---- final FC from fp32 h regs ----
    float* hf = (float*)(arena + HF_OFF);   // [16][64]
#pragma unroll
    for (int tt = 0; tt < 2; ++tt) {
        if (!act[tt]) continue;
        const int u = (wvf * 2 + tt) * 4 + grp;
        if (u < HID) hf[col * 64 + u] = hreg[tt];
    }
    __syncthreads();
    if (tid < ROWS * 3) {
        int m = tid / 3, o = tid - m * 3;
        float s = b_fc[o];
        for (int k = 0; k < HID; ++k)
            s += hf[m * 64 + k] * W_fc[o * HID + k];
        out[(size_t)(b0 + m) * 3 + o] = s;
    }
}

extern "C" void kernel_launch(void* const* d_in, const int* in_sizes, int n_in,
                              void* d_out, int out_size, void* d_ws, size_t ws_size,
                              hipStream_t stream) {
    const float* x    = (const float*)d_in[0];
    const float* W_ih = (const float*)d_in[1];
    const float* W_hh = (const float*)d_in[2];
    const float* b_ih = (const float*)d_in[3];
    const float* b_hh = (const float*)d_in[4];
    const float* W_fc = (const float*)d_in[5];
    const float* b_fc = (const float*)d_in[6];
    float* out = (float*)d_out;

    dim3 grid(4096 / ROWS);   // 256 blocks -> 1 per CU
    dim3 block(NTHREADS);     // 7 waves
    lstm_mfma10_kernel<<<grid, block, 0, stream>>>(x, W_ih, W_hh, b_ih, b_hh,
                                                   W_fc, b_fc, out);
}